// Round 17
// baseline (27.864 us; speedup 1.0000x reference)
//
#include <hip/hip_runtime.h>

static constexpr float INV_SQRT2 = 0.70710678118654752f;
static constexpr float INV_SQRT3 = 0.57735026918962576f;
static constexpr float SQRT2     = 1.41421356237309505f;
static constexpr float INV_SQRT6 = 0.40824829046386302f;

static constexpr int W_GRAPHS = 8;   // graphs per wave
static constexpr int B_GRAPHS = 32;  // graphs per block (4 waves)

// branchless fast tanh: 1 - 2/(exp(2x)+1); exact at +/-inf, err ~1e-7
__device__ __forceinline__ float fast_tanh(float x) {
    const float e = __builtin_amdgcn_exp2f(x * 2.8853900817779268f); // 2*log2(e)
    const float r = __builtin_amdgcn_rcpf(e + 1.0f);
    return fmaf(-2.0f, r, 1.0f);
}

__device__ __forceinline__ float gate_p(float k, float fw) { return k > 0.f ? k * fw : 0.f; }
__device__ __forceinline__ float gate_n(float k, float fw) { return k < 0.f ? k * fw : 0.f; }

// r13 skeleton (champion, 26.3us) + two latency cuts:
//  (a) SEEDED coop search: bnd[g] ~ 64g +/- <=8K (binomial bridge), so seed
//      at 64*target-8192 and descend 14 steps instead of 22. Wave-verify +
//      full-search fallback => correctness independent of distribution.
//  (b) 2 nodes/lane per iteration (128-node chunks, unguarded; odd chunk +
//      tail peeled) => half the latency-exposed waits, ZERO added masks.
// Prefix-accumulator routing (r15-validated).
__global__ __launch_bounds__(256) void e3nn_fused(
    const int*   __restrict__ z,
    const float* __restrict__ pos,
    const int*   __restrict__ batch,
    const float* __restrict__ w_tp,
    const float* __restrict__ fc_w,
    const float* __restrict__ fc_b,
    float*       __restrict__ out,
    int n, int n_graphs)
{
    const int tid  = threadIdx.x;
    const int wid  = tid >> 6;
    const int lane = tid & 63;
    const int bg0  = blockIdx.x * B_GRAPHS;
    if (bg0 >= n_graphs) return;

    __shared__ int sbnd[B_GRAPHS + 1];

    // ---- wave 0: seeded cooperative boundary search ----
    if (wid == 0) {
        const int tl     = (lane < B_GRAPHS) ? lane : B_GRAPHS;
        const int target = bg0 + tl;
        int lo0 = (target << 6) - 8192;
        lo0 = lo0 < 0 ? 0 : (lo0 > n ? n : lo0);
        int bv = lo0;
        #pragma unroll 1
        for (int step = 8192; step > 0; step >>= 1) {
            const int cand = bv + step;
            if (cand <= n && batch[cand - 1] < target) bv = cand;
        }
        const bool ok = (bv == 0 || batch[bv - 1] < target) &&
                        (bv >= n || batch[bv] >= target);
        if (!__all(ok)) {           // window missed (never, by construction)
            unsigned p2 = 1;
            while (p2 < (unsigned)n) p2 <<= 1;
            bv = 0;
            for (unsigned step = p2; step > 0; step >>= 1) {
                const unsigned cand = (unsigned)bv + step;
                if (cand <= (unsigned)n && batch[cand - 1] < target) bv = (int)cand;
            }
        }
        if (lane <= B_GRAPHS) sbnd[lane] = bv;
    }
    __syncthreads();

    // ---- uniform weight prep ----
    const float kA0 = w_tp[0] * INV_SQRT2;
    const float kA1 = w_tp[1] * INV_SQRT2;
    const float kB0 = w_tp[2] * (INV_SQRT3 * INV_SQRT2);
    const float kB1 = w_tp[3] * (INV_SQRT3 * INV_SQRT2);
    const float c0  = (w_tp[4] + w_tp[6]) * INV_SQRT2;
    const float c1  = (w_tp[5] + w_tp[7]) * INV_SQRT2;
    const float wE  = w_tp[8];
    const float fw0 = fc_w[0], fw1 = fc_w[1];
    const float fb  = fc_b[0];

    const float P0 = gate_p(c0, fc_w[2]) + gate_p(c1, fc_w[5]);
    const float N0 = gate_n(c0, fc_w[2]) + gate_n(c1, fc_w[5]);
    const float P1 = gate_p(c0, fc_w[3]) + gate_p(c1, fc_w[6]);
    const float N1 = gate_n(c0, fc_w[3]) + gate_n(c1, fc_w[6]);
    const float P2 = gate_p(c0, fc_w[4]) + gate_p(c1, fc_w[7]);
    const float N2 = gate_n(c0, fc_w[4]) + gate_n(c1, fc_w[7]);
    const float k8  = wE * SQRT2,     k11 = wE * INV_SQRT2, k12 = wE * INV_SQRT6;
    const float P8  = gate_p(k8,  fc_w[8]),  N8  = gate_n(k8,  fc_w[8]);
    const float P9  = gate_p(k8,  fc_w[9]),  N9  = gate_n(k8,  fc_w[9]);
    const float P10 = gate_p(k8,  fc_w[10]), N10 = gate_n(k8,  fc_w[10]);
    const float P11 = gate_p(k11, fc_w[11]), N11 = gate_n(k11, fc_w[11]);
    const float P12 = gate_p(k12, fc_w[12]), N12 = gate_n(k12, fc_w[12]);

    // ---- this wave's boundaries ----
    const int wb = wid * W_GRAPHS;
    const int B0 = sbnd[wb + 0], B1 = sbnd[wb + 1];
    const int B2 = sbnd[wb + 2], B3 = sbnd[wb + 3];
    const int B4 = sbnd[wb + 4], B5 = sbnd[wb + 5];
    const int B6 = sbnd[wb + 6], B7 = sbnd[wb + 7];
    const int B8 = sbnd[wb + 8];
    const int myb = sbnd[wb + ((lane < W_GRAPHS) ? lane : W_GRAPHS)];
    const int nbv = sbnd[wb + ((lane < W_GRAPHS) ? lane + 1 : W_GRAPHS)];

    float tot = 0.f, s1 = 0.f, s2 = 0.f, s3 = 0.f;
    float s4  = 0.f, s5 = 0.f, s6 = 0.f, s7 = 0.f;

    auto body = [&](int i, float sc, float v0, float v1, float v2, bool valid) {
        const float v00 = v0 * v0, v11 = v1 * v1, v22 = v2 * v2;
        const float ss  = sc * sc;
        const float dr  = v00 + v11 + v22;

        float acc = fb;
        const float x0 = fmaf(ss, kA0, dr * kB0);
        const float x1 = fmaf(ss, kA1, dr * kB1);
        acc = fmaf(fmaxf(x0, 0.f), fw0, acc);
        acc = fmaf(fmaxf(x1, 0.f), fw1, acc);

        const float sv0 = sc * v0, sv1 = sc * v1, sv2 = sc * v2;
        acc = fmaf(sv0, (sv0 > 0.f ? P0 : N0), acc);
        acc = fmaf(sv1, (sv1 > 0.f ? P1 : N1), acc);
        acc = fmaf(sv2, (sv2 > 0.f ? P2 : N2), acc);

        const float t8 = v0 * v1, t9 = v1 * v2, t10 = v0 * v2;
        acc = fmaf(t8,  (t8  > 0.f ? P8  : N8 ), acc);
        acc = fmaf(t9,  (t9  > 0.f ? P9  : N9 ), acc);
        acc = fmaf(t10, (t10 > 0.f ? P10 : N10), acc);

        const float t11 = v00 - v11;
        acc = fmaf(t11, (t11 > 0.f ? P11 : N11), acc);
        const float t12 = (v22 - v00) + (v22 - v11);
        acc = fmaf(t12, (t12 > 0.f ? P12 : N12), acc);

        float y = fast_tanh(acc);
        if (!valid) y = 0.f;   // folds away in full (unguarded) chunks

        tot += y;
        s1 += (i >= B1) ? y : 0.f;
        s2 += (i >= B2) ? y : 0.f;
        s3 += (i >= B3) ? y : 0.f;
        s4 += (i >= B4) ? y : 0.f;
        s5 += (i >= B5) ? y : 0.f;
        s6 += (i >= B6) ? y : 0.f;
        s7 += (i >= B7) ? y : 0.f;
    };

    const int T    = (B8 - B0) >> 6;      // full 64-node chunks
    const int endf = B0 + (T << 6);
    int base = B0;

    // 128-node iterations: 8 unguarded coalesced loads, 2 bodies
#pragma unroll 1
    for (; base + 128 <= endf; base += 128) {
        const int iA = base + lane;
        const int iB = iA + 64;
        const float scA = (float)z[iA];
        const float scB = (float)z[iB];
        const float a0 = pos[3 * iA], a1 = pos[3 * iA + 1], a2 = pos[3 * iA + 2];
        const float b0 = pos[3 * iB], b1 = pos[3 * iB + 1], b2 = pos[3 * iB + 2];
        body(iA, scA, a0, a1, a2, true);
        body(iB, scB, b0, b1, b2, true);
    }

    // possible single full 64-node chunk (unguarded)
    if (base < endf) {
        const int i = base + lane;
        const float sc = (float)z[i];
        const float v0 = pos[3 * i], v1 = pos[3 * i + 1], v2 = pos[3 * i + 2];
        body(i, sc, v0, v1, v2, true);
        base += 64;
    }

    // guarded tail (partial chunk)
    if (base < B8) {                      // wave-uniform
        const int i = base + lane;
        float sc = 0.f, v0 = 0.f, v1 = 0.f, v2 = 0.f;
        if (i < B8) {
            sc = (float)z[i];
            v0 = pos[3 * i]; v1 = pos[3 * i + 1]; v2 = pos[3 * i + 2];
        }
        body(i, sc, v0, v1, v2, i < B8);
    }

    // butterfly reductions (converged)
#pragma unroll
    for (int off = 32; off >= 1; off >>= 1) {
        tot += __shfl_xor(tot, off);
        s1  += __shfl_xor(s1,  off);
        s2  += __shfl_xor(s2,  off);
        s3  += __shfl_xor(s3,  off);
        s4  += __shfl_xor(s4,  off);
        s5  += __shfl_xor(s5,  off);
        s6  += __shfl_xor(s6,  off);
        s7  += __shfl_xor(s7,  off);
    }

    // per-graph sums from prefixes
    const float a0 = tot - s1, a1 = s1 - s2, a2 = s2 - s3, a3 = s3 - s4;
    const float a4 = s4 - s5,  a5 = s5 - s6, a6 = s6 - s7, a7 = s7;

    const int gw0 = bg0 + wid * W_GRAPHS;
    if (lane < W_GRAPHS && gw0 + lane < n_graphs) {
        float sel = (lane == 0) ? a0
                  : (lane == 1) ? a1
                  : (lane == 2) ? a2
                  : (lane == 3) ? a3
                  : (lane == 4) ? a4
                  : (lane == 5) ? a5
                  : (lane == 6) ? a6
                  :               a7;
        const float c = (float)(nbv - myb);
        out[gw0 + lane] = sel / fmaxf(c, 1.0f);
    }
}

extern "C" void kernel_launch(void* const* d_in, const int* in_sizes, int n_in,
                              void* d_out, int out_size, void* d_ws, size_t ws_size,
                              hipStream_t stream) {
    const int*   z     = (const int*)d_in[0];
    const float* pos   = (const float*)d_in[1];
    const int*   batch = (const int*)d_in[2];
    const float* w_tp  = (const float*)d_in[3];
    const float* fc_w  = (const float*)d_in[4];
    const float* fc_b  = (const float*)d_in[5];

    float* out = (float*)d_out;
    const int n        = in_sizes[0];
    const int n_graphs = out_size;

    const int blocks = (n_graphs + B_GRAPHS - 1) / B_GRAPHS;
    e3nn_fused<<<blocks, 256, 0, stream>>>(z, pos, batch, w_tp, fc_w, fc_b,
                                           out, n, n_graphs);
}

// Round 18
// 26.573 us; speedup vs baseline: 1.0486x; 1.0486x over previous
//
#include <hip/hip_runtime.h>

static constexpr float INV_SQRT2 = 0.70710678118654752f;
static constexpr float INV_SQRT3 = 0.57735026918962576f;
static constexpr float SQRT2     = 1.41421356237309505f;
static constexpr float INV_SQRT6 = 0.40824829046386302f;

static constexpr int W_GRAPHS = 8;   // graphs per wave
static constexpr int B_GRAPHS = 32;  // graphs per block (4 waves)

// branchless fast tanh: 1 - 2/(exp(2x)+1); exact at +/-inf, err ~1e-7
__device__ __forceinline__ float fast_tanh(float x) {
    const float e = __builtin_amdgcn_exp2f(x * 2.8853900817779268f); // 2*log2(e)
    const float r = __builtin_amdgcn_rcpf(e + 1.0f);
    return fmaf(-2.0f, r, 1.0f);
}

__device__ __forceinline__ float gate_p(float k, float fw) { return k > 0.f ? k * fw : 0.f; }
__device__ __forceinline__ float gate_n(float k, float fw) { return k < 0.f ? k * fw : 0.f; }

struct F3 { float x, y, zc; };   // 4-byte aligned; loads as global_load_dwordx3

// r13 champion skeleton (coop search + plain 1-node/lane loop) with two
// pure VALU/VMEM reductions, nothing else changed:
//  (a) pos loaded as ONE F3 (dwordx3) instead of 3 scalar loads: 4 -> 2
//      load issues + half the 64-bit address chains per iteration.
//  (b) prefix-accumulator routing (r15-validated): tot,s1..s7 and
//      a_k = s_k - s_{k+1}; drops 7 boolean combines per node.
__global__ __launch_bounds__(256) void e3nn_fused(
    const int*   __restrict__ z,
    const float* __restrict__ pos,
    const int*   __restrict__ batch,
    const float* __restrict__ w_tp,
    const float* __restrict__ fc_w,
    const float* __restrict__ fc_b,
    float*       __restrict__ out,
    int n, int n_graphs)
{
    const int tid  = threadIdx.x;
    const int wid  = tid >> 6;
    const int lane = tid & 63;
    const int bg0  = blockIdx.x * B_GRAPHS;
    if (bg0 >= n_graphs) return;

    __shared__ int sbnd[B_GRAPHS + 1];

    // ---- wave 0: cooperative boundary search (one 22-probe chain/block) ----
    if (wid == 0) {
        const int tl     = (lane < B_GRAPHS) ? lane : B_GRAPHS;
        const int target = bg0 + tl;
        unsigned p2 = 1;
        while (p2 < (unsigned)n) p2 <<= 1;
        int bv = 0;
        for (unsigned step = p2 >> 1; step > 0; step >>= 1) {
            const unsigned cand = (unsigned)bv + step;
            if (cand <= (unsigned)n && batch[cand - 1] < target) bv = (int)cand;
        }
        if (lane <= B_GRAPHS) sbnd[lane] = bv;
    }
    __syncthreads();

    // ---- uniform weight prep ----
    const float kA0 = w_tp[0] * INV_SQRT2;
    const float kA1 = w_tp[1] * INV_SQRT2;
    const float kB0 = w_tp[2] * (INV_SQRT3 * INV_SQRT2);
    const float kB1 = w_tp[3] * (INV_SQRT3 * INV_SQRT2);
    const float c0  = (w_tp[4] + w_tp[6]) * INV_SQRT2;
    const float c1  = (w_tp[5] + w_tp[7]) * INV_SQRT2;
    const float wE  = w_tp[8];
    const float fw0 = fc_w[0], fw1 = fc_w[1];
    const float fb  = fc_b[0];

    const float P0 = gate_p(c0, fc_w[2]) + gate_p(c1, fc_w[5]);
    const float N0 = gate_n(c0, fc_w[2]) + gate_n(c1, fc_w[5]);
    const float P1 = gate_p(c0, fc_w[3]) + gate_p(c1, fc_w[6]);
    const float N1 = gate_n(c0, fc_w[3]) + gate_n(c1, fc_w[6]);
    const float P2 = gate_p(c0, fc_w[4]) + gate_p(c1, fc_w[7]);
    const float N2 = gate_n(c0, fc_w[4]) + gate_n(c1, fc_w[7]);
    const float k8  = wE * SQRT2,     k11 = wE * INV_SQRT2, k12 = wE * INV_SQRT6;
    const float P8  = gate_p(k8,  fc_w[8]),  N8  = gate_n(k8,  fc_w[8]);
    const float P9  = gate_p(k8,  fc_w[9]),  N9  = gate_n(k8,  fc_w[9]);
    const float P10 = gate_p(k8,  fc_w[10]), N10 = gate_n(k8,  fc_w[10]);
    const float P11 = gate_p(k11, fc_w[11]), N11 = gate_n(k11, fc_w[11]);
    const float P12 = gate_p(k12, fc_w[12]), N12 = gate_n(k12, fc_w[12]);

    // ---- this wave's boundaries ----
    const int wb = wid * W_GRAPHS;
    const int B0 = sbnd[wb + 0], B1 = sbnd[wb + 1];
    const int B2 = sbnd[wb + 2], B3 = sbnd[wb + 3];
    const int B4 = sbnd[wb + 4], B5 = sbnd[wb + 5];
    const int B6 = sbnd[wb + 6], B7 = sbnd[wb + 7];
    const int B8 = sbnd[wb + 8];
    const int myb = sbnd[wb + ((lane < W_GRAPHS) ? lane : W_GRAPHS)];
    const int nbv = sbnd[wb + ((lane < W_GRAPHS) ? lane + 1 : W_GRAPHS)];

    float tot = 0.f, s1 = 0.f, s2 = 0.f, s3 = 0.f;
    float s4  = 0.f, s5 = 0.f, s6 = 0.f, s7 = 0.f;

#pragma unroll 1
    for (int base = B0; base < B8; base += 64) {
        const int i = base + lane;
        if (i < B8) {
            const float sc = (float)z[i];
            const F3    p  = *reinterpret_cast<const F3*>(pos + 3 * i);
            const float v0 = p.x, v1 = p.y, v2 = p.zc;

            const float v00 = v0 * v0, v11 = v1 * v1, v22 = v2 * v2;
            const float ss  = sc * sc;
            const float dr  = v00 + v11 + v22;

            float acc = fb;
            const float x0 = fmaf(ss, kA0, dr * kB0);
            const float x1 = fmaf(ss, kA1, dr * kB1);
            acc = fmaf(fmaxf(x0, 0.f), fw0, acc);
            acc = fmaf(fmaxf(x1, 0.f), fw1, acc);

            const float sv0 = sc * v0, sv1 = sc * v1, sv2 = sc * v2;
            acc = fmaf(sv0, (sv0 > 0.f ? P0 : N0), acc);
            acc = fmaf(sv1, (sv1 > 0.f ? P1 : N1), acc);
            acc = fmaf(sv2, (sv2 > 0.f ? P2 : N2), acc);

            const float t8 = v0 * v1, t9 = v1 * v2, t10 = v0 * v2;
            acc = fmaf(t8,  (t8  > 0.f ? P8  : N8 ), acc);
            acc = fmaf(t9,  (t9  > 0.f ? P9  : N9 ), acc);
            acc = fmaf(t10, (t10 > 0.f ? P10 : N10), acc);

            const float t11 = v00 - v11;
            acc = fmaf(t11, (t11 > 0.f ? P11 : N11), acc);
            const float t12 = (v22 - v00) + (v22 - v11);
            acc = fmaf(t12, (t12 > 0.f ? P12 : N12), acc);

            const float y = fast_tanh(acc);

            tot += y;
            s1 += (i >= B1) ? y : 0.f;
            s2 += (i >= B2) ? y : 0.f;
            s3 += (i >= B3) ? y : 0.f;
            s4 += (i >= B4) ? y : 0.f;
            s5 += (i >= B5) ? y : 0.f;
            s6 += (i >= B6) ? y : 0.f;
            s7 += (i >= B7) ? y : 0.f;
        }
    }

    // butterfly reductions (converged)
#pragma unroll
    for (int off = 32; off >= 1; off >>= 1) {
        tot += __shfl_xor(tot, off);
        s1  += __shfl_xor(s1,  off);
        s2  += __shfl_xor(s2,  off);
        s3  += __shfl_xor(s3,  off);
        s4  += __shfl_xor(s4,  off);
        s5  += __shfl_xor(s5,  off);
        s6  += __shfl_xor(s6,  off);
        s7  += __shfl_xor(s7,  off);
    }

    // per-graph sums from prefixes
    const float a0 = tot - s1, a1 = s1 - s2, a2 = s2 - s3, a3 = s3 - s4;
    const float a4 = s4 - s5,  a5 = s5 - s6, a6 = s6 - s7, a7 = s7;

    const int gw0 = bg0 + wid * W_GRAPHS;
    if (lane < W_GRAPHS && gw0 + lane < n_graphs) {
        float sel = (lane == 0) ? a0
                  : (lane == 1) ? a1
                  : (lane == 2) ? a2
                  : (lane == 3) ? a3
                  : (lane == 4) ? a4
                  : (lane == 5) ? a5
                  : (lane == 6) ? a6
                  :               a7;
        const float c = (float)(nbv - myb);
        out[gw0 + lane] = sel / fmaxf(c, 1.0f);
    }
}

extern "C" void kernel_launch(void* const* d_in, const int* in_sizes, int n_in,
                              void* d_out, int out_size, void* d_ws, size_t ws_size,
                              hipStream_t stream) {
    const int*   z     = (const int*)d_in[0];
    const float* pos   = (const float*)d_in[1];
    const int*   batch = (const int*)d_in[2];
    const float* w_tp  = (const float*)d_in[3];
    const float* fc_w  = (const float*)d_in[4];
    const float* fc_b  = (const float*)d_in[5];

    float* out = (float*)d_out;
    const int n        = in_sizes[0];
    const int n_graphs = out_size;

    const int blocks = (n_graphs + B_GRAPHS - 1) / B_GRAPHS;
    e3nn_fused<<<blocks, 256, 0, stream>>>(z, pos, batch, w_tp, fc_w, fc_b,
                                           out, n, n_graphs);
}

// Round 19
// 26.313 us; speedup vs baseline: 1.0589x; 1.0099x over previous
//
#include <hip/hip_runtime.h>

static constexpr float INV_SQRT2 = 0.70710678118654752f;
static constexpr float INV_SQRT3 = 0.57735026918962576f;
static constexpr float SQRT2     = 1.41421356237309505f;
static constexpr float INV_SQRT6 = 0.40824829046386302f;

static constexpr int W_GRAPHS = 8;   // graphs per wave
static constexpr int B_GRAPHS = 64;  // graphs per block (8 waves, 512 thr)

// branchless fast tanh: 1 - 2/(exp(2x)+1); exact at +/-inf, err ~1e-7
__device__ __forceinline__ float fast_tanh(float x) {
    const float e = __builtin_amdgcn_exp2f(x * 2.8853900817779268f); // 2*log2(e)
    const float r = __builtin_amdgcn_rcpf(e + 1.0f);
    return fmaf(-2.0f, r, 1.0f);
}

__device__ __forceinline__ float gate_p(float k, float fw) { return k > 0.f ? k * fw : 0.f; }
__device__ __forceinline__ float gate_n(float k, float fw) { return k < 0.f ? k * fw : 0.f; }

struct F3 { float x, y, zc; };   // loads as global_load_dwordx3

// r18 body, restructured to 512-thread blocks (8 waves, 64 graphs/block):
// full per-CU residency needs only 4 blocks/CU (vs 8 with 256-thr blocks) --
// tests the occupancy-limited theory (Occupancy stuck at 41-65% across all
// prior rounds). Also halves the serial search chains: wave 0 covers 64
// boundary targets, wave 1 lane 0 covers the 65th.
__global__ __launch_bounds__(512) void e3nn_fused(
    const int*   __restrict__ z,
    const float* __restrict__ pos,
    const int*   __restrict__ batch,
    const float* __restrict__ w_tp,
    const float* __restrict__ fc_w,
    const float* __restrict__ fc_b,
    float*       __restrict__ out,
    int n, int n_graphs)
{
    const int tid  = threadIdx.x;
    const int wid  = tid >> 6;
    const int lane = tid & 63;
    const int bg0  = blockIdx.x * B_GRAPHS;
    if (bg0 >= n_graphs) return;

    __shared__ int sbnd[B_GRAPHS + 1];

    // ---- cooperative boundary search ----
    if (wid == 0) {
        int target = bg0 + lane;
        if (target > n_graphs) target = n_graphs;
        unsigned p2 = 1;
        while (p2 < (unsigned)n) p2 <<= 1;
        int bv = 0;
        for (unsigned step = p2 >> 1; step > 0; step >>= 1) {
            const unsigned cand = (unsigned)bv + step;
            if (cand <= (unsigned)n && batch[cand - 1] < target) bv = (int)cand;
        }
        sbnd[lane] = bv;
    } else if (wid == 1 && lane == 0) {
        int target = bg0 + B_GRAPHS;
        if (target > n_graphs) target = n_graphs;
        unsigned p2 = 1;
        while (p2 < (unsigned)n) p2 <<= 1;
        int bv = 0;
        for (unsigned step = p2 >> 1; step > 0; step >>= 1) {
            const unsigned cand = (unsigned)bv + step;
            if (cand <= (unsigned)n && batch[cand - 1] < target) bv = (int)cand;
        }
        sbnd[B_GRAPHS] = bv;
    }
    __syncthreads();

    // ---- uniform weight prep ----
    const float kA0 = w_tp[0] * INV_SQRT2;
    const float kA1 = w_tp[1] * INV_SQRT2;
    const float kB0 = w_tp[2] * (INV_SQRT3 * INV_SQRT2);
    const float kB1 = w_tp[3] * (INV_SQRT3 * INV_SQRT2);
    const float c0  = (w_tp[4] + w_tp[6]) * INV_SQRT2;
    const float c1  = (w_tp[5] + w_tp[7]) * INV_SQRT2;
    const float wE  = w_tp[8];
    const float fw0 = fc_w[0], fw1 = fc_w[1];
    const float fb  = fc_b[0];

    const float P0 = gate_p(c0, fc_w[2]) + gate_p(c1, fc_w[5]);
    const float N0 = gate_n(c0, fc_w[2]) + gate_n(c1, fc_w[5]);
    const float P1 = gate_p(c0, fc_w[3]) + gate_p(c1, fc_w[6]);
    const float N1 = gate_n(c0, fc_w[3]) + gate_n(c1, fc_w[6]);
    const float P2 = gate_p(c0, fc_w[4]) + gate_p(c1, fc_w[7]);
    const float N2 = gate_n(c0, fc_w[4]) + gate_n(c1, fc_w[7]);
    const float k8  = wE * SQRT2,     k11 = wE * INV_SQRT2, k12 = wE * INV_SQRT6;
    const float P8  = gate_p(k8,  fc_w[8]),  N8  = gate_n(k8,  fc_w[8]);
    const float P9  = gate_p(k8,  fc_w[9]),  N9  = gate_n(k8,  fc_w[9]);
    const float P10 = gate_p(k8,  fc_w[10]), N10 = gate_n(k8,  fc_w[10]);
    const float P11 = gate_p(k11, fc_w[11]), N11 = gate_n(k11, fc_w[11]);
    const float P12 = gate_p(k12, fc_w[12]), N12 = gate_n(k12, fc_w[12]);

    // ---- this wave's boundaries ----
    const int wb = wid * W_GRAPHS;
    const int B0 = sbnd[wb + 0], B1 = sbnd[wb + 1];
    const int B2 = sbnd[wb + 2], B3 = sbnd[wb + 3];
    const int B4 = sbnd[wb + 4], B5 = sbnd[wb + 5];
    const int B6 = sbnd[wb + 6], B7 = sbnd[wb + 7];
    const int B8 = sbnd[wb + 8];
    const int myb = sbnd[wb + ((lane < W_GRAPHS) ? lane : W_GRAPHS)];
    const int nbv = sbnd[wb + ((lane < W_GRAPHS) ? lane + 1 : W_GRAPHS)];

    float tot = 0.f, s1 = 0.f, s2 = 0.f, s3 = 0.f;
    float s4  = 0.f, s5 = 0.f, s6 = 0.f, s7 = 0.f;

#pragma unroll 1
    for (int base = B0; base < B8; base += 64) {
        const int i = base + lane;
        if (i < B8) {
            const float sc = (float)z[i];
            const F3    p  = *reinterpret_cast<const F3*>(pos + 3 * i);
            const float v0 = p.x, v1 = p.y, v2 = p.zc;

            const float v00 = v0 * v0, v11 = v1 * v1, v22 = v2 * v2;
            const float ss  = sc * sc;
            const float dr  = v00 + v11 + v22;

            float acc = fb;
            const float x0 = fmaf(ss, kA0, dr * kB0);
            const float x1 = fmaf(ss, kA1, dr * kB1);
            acc = fmaf(fmaxf(x0, 0.f), fw0, acc);
            acc = fmaf(fmaxf(x1, 0.f), fw1, acc);

            const float sv0 = sc * v0, sv1 = sc * v1, sv2 = sc * v2;
            acc = fmaf(sv0, (sv0 > 0.f ? P0 : N0), acc);
            acc = fmaf(sv1, (sv1 > 0.f ? P1 : N1), acc);
            acc = fmaf(sv2, (sv2 > 0.f ? P2 : N2), acc);

            const float t8 = v0 * v1, t9 = v1 * v2, t10 = v0 * v2;
            acc = fmaf(t8,  (t8  > 0.f ? P8  : N8 ), acc);
            acc = fmaf(t9,  (t9  > 0.f ? P9  : N9 ), acc);
            acc = fmaf(t10, (t10 > 0.f ? P10 : N10), acc);

            const float t11 = v00 - v11;
            acc = fmaf(t11, (t11 > 0.f ? P11 : N11), acc);
            const float t12 = (v22 - v00) + (v22 - v11);
            acc = fmaf(t12, (t12 > 0.f ? P12 : N12), acc);

            const float y = fast_tanh(acc);

            tot += y;
            s1 += (i >= B1) ? y : 0.f;
            s2 += (i >= B2) ? y : 0.f;
            s3 += (i >= B3) ? y : 0.f;
            s4 += (i >= B4) ? y : 0.f;
            s5 += (i >= B5) ? y : 0.f;
            s6 += (i >= B6) ? y : 0.f;
            s7 += (i >= B7) ? y : 0.f;
        }
    }

    // butterfly reductions (converged)
#pragma unroll
    for (int off = 32; off >= 1; off >>= 1) {
        tot += __shfl_xor(tot, off);
        s1  += __shfl_xor(s1,  off);
        s2  += __shfl_xor(s2,  off);
        s3  += __shfl_xor(s3,  off);
        s4  += __shfl_xor(s4,  off);
        s5  += __shfl_xor(s5,  off);
        s6  += __shfl_xor(s6,  off);
        s7  += __shfl_xor(s7,  off);
    }

    // per-graph sums from prefixes
    const float a0 = tot - s1, a1 = s1 - s2, a2 = s2 - s3, a3 = s3 - s4;
    const float a4 = s4 - s5,  a5 = s5 - s6, a6 = s6 - s7, a7 = s7;

    const int gw0 = bg0 + wid * W_GRAPHS;
    if (lane < W_GRAPHS && gw0 + lane < n_graphs) {
        float sel = (lane == 0) ? a0
                  : (lane == 1) ? a1
                  : (lane == 2) ? a2
                  : (lane == 3) ? a3
                  : (lane == 4) ? a4
                  : (lane == 5) ? a5
                  : (lane == 6) ? a6
                  :               a7;
        const float c = (float)(nbv - myb);
        out[gw0 + lane] = sel / fmaxf(c, 1.0f);
    }
}

extern "C" void kernel_launch(void* const* d_in, const int* in_sizes, int n_in,
                              void* d_out, int out_size, void* d_ws, size_t ws_size,
                              hipStream_t stream) {
    const int*   z     = (const int*)d_in[0];
    const float* pos   = (const float*)d_in[1];
    const int*   batch = (const int*)d_in[2];
    const float* w_tp  = (const float*)d_in[3];
    const float* fc_w  = (const float*)d_in[4];
    const float* fc_b  = (const float*)d_in[5];

    float* out = (float*)d_out;
    const int n        = in_sizes[0];
    const int n_graphs = out_size;

    const int blocks = (n_graphs + B_GRAPHS - 1) / B_GRAPHS;
    e3nn_fused<<<blocks, 512, 0, stream>>>(z, pos, batch, w_tp, fc_w, fc_b,
                                           out, n, n_graphs);
}